// Round 4
// baseline (337.184 us; speedup 1.0000x reference)
//
#include <hip/hip_runtime.h>

// CapsClass2d dynamic routing — MFMA 16x16x16, global_load_lds pipelined.
// b=256, P=1152, C=10, os=is=16, 3 iterations.
//
// R2 post-mortem: ~2000 cy per wave-position of pure vmcnt stall, identical
// across divergent/unconditional/paired load variants -> plain register loads
// never pipeline. Fix = m97 pattern: async global_load_lds staging into
// per-wave double-buffered LDS + counted inline-asm vmcnt (never 0 in steady
// state), ds_read_b64 -> MFMA. Loads stay in flight without consuming VGPRs.
//
// R3 fixes: (a) host-pass __has_builtin(amdgcn mfma)==false -> 3rd branch
// (stub body, never executed on host; device pass verified to have the
// builtin in R3's log). (b) coup_lds removed: it pushed IT=2 to 66KB LDS ->
// occupancy 1 wave/EU. coup now written directly (p innermost -> L2
// write-back coalesces). All instantiations: 51.3KB LDS -> 3 blocks/CU.
// (c) IT=2 store/vmcnt hygiene: coup stores issued BEFORE restage GLL so the
// next vmcnt(5) drains [old buf + stores] and leaves the prefetch in flight.
//
// MFMA 16x16x16 (K=16 exact): all 64 lanes carry data (8B/lane frags).
//   A[m=o][k=i]: m=lane&15, k=(lane>>4)*4+j
//   B[k=i][n=b]: n=lane&15, k=(lane>>4)*4+j
//   C/D: col(b)=lane&15, row(o)=(lane>>4)*4+reg
// Wave = 16 batches x 10 c x PW=6 positions; block = 4 waves same b-tile.
// Grid 48x16 = 768 = 256 CU x 3 blocks. Merge: LDS -> part[PBLK][b][j].

#define NPOS 1152
#define NC 10
#define OS 16
#define IS 16
#define NB 256
#define CO (NC * OS)            // 160
#define CAPS_EPS 1e-8f
#define PW 6                    // positions per wave
#define PBLK (NPOS / (4 * PW))  // 48 p-superblocks
#define PPB (4 * PW)            // 24 positions per block
#define NA2 (NPOS * NC * 64)    // A uint2 slots (737280, 5.9 MB)
#define NB2 (16 * NPOS * 64)    // B uint2 slots (1179648, 9.4 MB)
#define LDS_AU 1280             // u32 words per A buffer (5120 B = 10 frags)

typedef __attribute__((ext_vector_type(4))) short bf16x4;
typedef __attribute__((ext_vector_type(4))) _Float16 halfx4;
typedef __attribute__((ext_vector_type(4))) float floatx4;

// Branch 1: bf16 (present on gfx950 device pass, verified R3 log).
// Branch 0: f16 fallback. Branch 2: host pass / unavailable -> inert stub.
#if __has_builtin(__builtin_amdgcn_mfma_f32_16x16x16bf16_1k)
  #define MFMA_KIND 1
#elif __has_builtin(__builtin_amdgcn_mfma_f32_16x16x16f16)
  #define MFMA_KIND 0
#else
  #define MFMA_KIND 2
#endif

#define GLL(gp, lp) __builtin_amdgcn_global_load_lds( \
    (const __attribute__((address_space(1))) unsigned int*)(gp), \
    (__attribute__((address_space(3))) unsigned int*)(lp), 16, 0, 0)

__device__ __forceinline__ unsigned f2bf_rne(float x) {
    union { float f; unsigned u; } v; v.f = x;
    return (v.u + 0x7FFFu + ((v.u >> 16) & 1u)) >> 16;
}

__device__ __forceinline__ uint2 pack4(float4 f) {
#if MFMA_KIND != 0
    uint2 r;
    r.x = f2bf_rne(f.x) | (f2bf_rne(f.y) << 16);
    r.y = f2bf_rne(f.z) | (f2bf_rne(f.w) << 16);
    return r;
#else
    union { uint2 u; halfx4 v; } r;
    r.v[0] = (_Float16)f.x; r.v[1] = (_Float16)f.y;
    r.v[2] = (_Float16)f.z; r.v[3] = (_Float16)f.w;
    return r.u;
#endif
}

__device__ __forceinline__ floatx4 MFMA16(uint2 a, uint2 b, floatx4 c) {
#if MFMA_KIND == 1
    union { uint2 u; bf16x4 v; } A, B; A.u = a; B.u = b;
    return __builtin_amdgcn_mfma_f32_16x16x16bf16_1k(A.v, B.v, c, 0, 0, 0);
#elif MFMA_KIND == 0
    union { uint2 u; halfx4 v; } A, B; A.u = a; B.u = b;
    return __builtin_amdgcn_mfma_f32_16x16x16f16(A.v, B.v, c, 0, 0, 0);
#else
    (void)a; (void)b;
    return c;   // host pass stub — never executed
#endif
}

// Pre-convert W and poses into 16x16x16 fragment-layout buffers (8B/lane/frag).
// wsA slot (p*10+c)*64+L : W[p][c][o=L&15][i=(L>>4)*4 ..+3]
// wsB slot (bt*1152+p)*64+L : X[bt*16+(L&15)][p][(L>>4)*4 ..+3]   (bt-major!)
__global__ __launch_bounds__(256) void preconv2_kernel(
    const float* __restrict__ poses, const float* __restrict__ weight,
    uint2* __restrict__ wsA, uint2* __restrict__ wsB)
{
    const int gid = blockIdx.x * 256 + threadIdx.x;
    if (gid < NA2) {
        const int L = gid & 63, pc = gid >> 6;
        const float4 src = *(const float4*)(weight + (size_t)pc * 256 + (L & 15) * 16 + (L >> 4) * 4);
        wsA[gid] = pack4(src);
    } else {
        const int s = gid - NA2;
        if (s < NB2) {
            const int L = s & 63, bp = s >> 6;
            const int p = bp % NPOS, bt = bp / NPOS;
            const float4 src = *(const float4*)(poses +
                ((size_t)(bt * 16 + (L & 15)) * NPOS + p) * IS + (L >> 4) * 4);
            wsB[s] = pack4(src);
        }
    }
}

template <int IT>
__global__ __launch_bounds__(256, 3) void caps_votes3(
    const uint2* __restrict__ wsA, const uint2* __restrict__ wsB,
    const float* __restrict__ vsum, float* __restrict__ part,
    float* __restrict__ out_coup)
{
    const int t    = threadIdx.x;
    const int wave = t >> 6, lane = t & 63;
    const int bcol = lane & 15, quad = lane >> 4;
    const int bt   = blockIdx.y;
    const int b0   = bt * 16;
    const int pbase = blockIdx.x * PPB + wave * PW;

    __shared__ unsigned ldsA[4][2][LDS_AU];     // per-wave A double buffer (40 KB)
    __shared__ float s_lds[16 * 161];           // merge buffer (+1 pad)

    for (int k = t; k < 16 * 161; k += 256) s_lds[k] = 0.f;

    float4 vs[NC];
    if (IT > 0) {
        const float* vp = vsum + (size_t)(b0 + bcol) * CO + quad * 4;
#pragma unroll
        for (int c = 0; c < NC; ++c) vs[c] = *(const float4*)(vp + c * 16);
    }
    __syncthreads();

    // B frags for all PW positions -> VGPRs (6 independent 8B loads)
    uint2 bfr[PW];
    {
        const uint2* bp = wsB + ((size_t)bt * NPOS + pbase) * 64 + lane;
#pragma unroll
        for (int pi = 0; pi < PW; ++pi) bfr[pi] = bp[pi * 64];
    }

    // A staging: per-wave lds double buffer; 5 x 1024B gll per position.
    const char* gA = (const char*)(wsA + (size_t)pbase * NC * 64) + lane * 16;
    unsigned* lA = &ldsA[wave][0][0];
#pragma unroll
    for (int ch = 0; ch < 5; ++ch) GLL(gA + ch * 1024, lA + ch * 256);
#pragma unroll
    for (int ch = 0; ch < 5; ++ch) GLL(gA + 5120 + ch * 1024, lA + LDS_AU + ch * 256);

    floatx4 sacc[NC];
#pragma unroll
    for (int c = 0; c < NC; ++c) sacc[c] = (floatx4)(0.f);

#pragma unroll
    for (int pi = 0; pi < PW; ++pi) {
        unsigned* buf = lA + (pi & 1) * LDS_AU;
        // counted wait: current buffer (and B regs / prior stores) landed;
        // next buffer's 5 loads stay in flight.
        if (pi < PW - 1) { asm volatile("s_waitcnt vmcnt(5)" ::: "memory"); }
        else             { asm volatile("s_waitcnt vmcnt(0)" ::: "memory"); }

        uint2 af[NC];
#pragma unroll
        for (int c = 0; c < NC; ++c)
            af[c] = *(const uint2*)((const char*)buf + c * 512 + lane * 8);

        if (IT == 0) {
#pragma unroll
            for (int c = 0; c < NC; ++c) sacc[c] = MFMA16(af[c], bfr[pi], sacc[c]);
            if (pi < PW - 2) {
                asm volatile("s_waitcnt lgkmcnt(0)" ::: "memory");  // ds_reads of buf done
                const char* g = gA + (size_t)(pi + 2) * 5120;
#pragma unroll
                for (int ch = 0; ch < 5; ++ch) GLL(g + ch * 1024, buf + ch * 256);
            }
        } else {
            floatx4 acc[NC];
#pragma unroll
            for (int c = 0; c < NC; ++c) acc[c] = MFMA16(af[c], bfr[pi], (floatx4)(0.f));

            // logits: dot over o = (quad,reg); 4 FMA + 2 shfl per c
            float lg[NC];
            float mx = -1e30f;
#pragma unroll
            for (int c = 0; c < NC; ++c) {
                float pt = vs[c].x * acc[c][0] + vs[c].y * acc[c][1]
                         + vs[c].z * acc[c][2] + vs[c].w * acc[c][3];
                pt += __shfl_xor(pt, 16);
                pt += __shfl_xor(pt, 32);
                lg[c] = pt;
                mx = fmaxf(mx, pt);
            }
            float coup[NC];
            float sum = 0.f;
#pragma unroll
            for (int c = 0; c < NC; ++c) { coup[c] = __expf(lg[c] - mx); sum += coup[c]; }
            const float inv = 1.f / sum;
#pragma unroll
            for (int c = 0; c < NC; ++c) coup[c] *= inv;

            if (IT == 2 && quad == 0) {
                // direct scatter; p is innermost out_coup dim -> L2 write-back
                // coalesces across the loop. Issued BEFORE restage GLL so the
                // next vmcnt(5) drains these, not the prefetch.
                float* cp = out_coup + (size_t)(b0 + bcol) * (NC * NPOS) + (pbase + pi);
#pragma unroll
                for (int c = 0; c < NC; ++c) cp[c * NPOS] = coup[c];
            }

            if (pi < PW - 2) {
                asm volatile("s_waitcnt lgkmcnt(0)" ::: "memory");  // ds_reads of buf done
                const char* g = gA + (size_t)(pi + 2) * 5120;
#pragma unroll
                for (int ch = 0; ch < 5; ++ch) GLL(g + ch * 1024, buf + ch * 256);
            }

#pragma unroll
            for (int c = 0; c < NC; ++c)
#pragma unroll
                for (int r = 0; r < 4; ++r) sacc[c][r] += coup[c] * acc[c][r];
        }
    }

    // merge the block's 4 waves in LDS, then coalesced partial store
    const float scale = (IT == 0) ? 0.1f : 1.f;
#pragma unroll
    for (int c = 0; c < NC; ++c)
#pragma unroll
        for (int r = 0; r < 4; ++r)
            atomicAdd(&s_lds[bcol * 161 + c * 16 + quad * 4 + r], scale * sacc[c][r]);
    __syncthreads();

    float* pp = part + ((size_t)blockIdx.x * NB + b0) * CO;
    for (int k = t; k < 16 * CO; k += 256) {
        const int b = k / CO, j = k - b * CO;
        pp[(size_t)b * CO + j] = s_lds[b * 161 + j];
    }
}

// Fallback (tiny ws): direct float4 loads + in-register conversion, atomic merge.
__global__ __launch_bounds__(256) void caps_votes_fb(
    const float* __restrict__ poses, const float* __restrict__ weight,
    const float* __restrict__ vsum, float* __restrict__ sbuf,
    float* __restrict__ out_coup, int it)
{
    const int t = threadIdx.x, wave = t >> 6, lane = t & 63;
    const int bcol = lane & 15, quad = lane >> 4;
    const int bt = blockIdx.y, b0 = bt * 16;
    const int pbase = blockIdx.x * PPB + wave * PW;

    __shared__ float s_lds[16 * 161];
    for (int k = t; k < 16 * 161; k += 256) s_lds[k] = 0.f;

    float4 vs[NC];
    if (it > 0) {
        const float* vp = vsum + (size_t)(b0 + bcol) * CO + quad * 4;
#pragma unroll
        for (int c = 0; c < NC; ++c) vs[c] = *(const float4*)(vp + c * 16);
    }
    __syncthreads();

    floatx4 sacc[NC];
#pragma unroll
    for (int c = 0; c < NC; ++c) sacc[c] = (floatx4)(0.f);

    for (int pi = 0; pi < PW; ++pi) {
        const int p = pbase + pi;
        const uint2 bfrag = pack4(*(const float4*)(poses +
            ((size_t)(b0 + bcol) * NPOS + p) * IS + quad * 4));
        floatx4 acc[NC];
#pragma unroll
        for (int c = 0; c < NC; ++c) {
            const uint2 a = pack4(*(const float4*)(weight +
                (size_t)(p * NC + c) * 256 + bcol * 16 + quad * 4));
            acc[c] = MFMA16(a, bfrag, (floatx4)(0.f));
        }
        if (it == 0) {
#pragma unroll
            for (int c = 0; c < NC; ++c)
#pragma unroll
                for (int r = 0; r < 4; ++r) sacc[c][r] += acc[c][r];
        } else {
            float lg[NC], mx = -1e30f;
#pragma unroll
            for (int c = 0; c < NC; ++c) {
                float pt = vs[c].x * acc[c][0] + vs[c].y * acc[c][1]
                         + vs[c].z * acc[c][2] + vs[c].w * acc[c][3];
                pt += __shfl_xor(pt, 16);
                pt += __shfl_xor(pt, 32);
                lg[c] = pt; mx = fmaxf(mx, pt);
            }
            float coup[NC], sum = 0.f;
#pragma unroll
            for (int c = 0; c < NC; ++c) { coup[c] = __expf(lg[c] - mx); sum += coup[c]; }
            const float inv = 1.f / sum;
#pragma unroll
            for (int c = 0; c < NC; ++c) coup[c] *= inv;
            if (it == 2 && quad == 0) {
                float* cp = out_coup + (size_t)(b0 + bcol) * (NC * NPOS) + p;
#pragma unroll
                for (int c = 0; c < NC; ++c) cp[c * NPOS] = coup[c];
            }
#pragma unroll
            for (int c = 0; c < NC; ++c)
#pragma unroll
                for (int r = 0; r < 4; ++r) sacc[c][r] += coup[c] * acc[c][r];
        }
    }

    const float scale = (it == 0) ? 0.1f : 1.f;
#pragma unroll
    for (int c = 0; c < NC; ++c)
#pragma unroll
        for (int r = 0; r < 4; ++r)
            atomicAdd(&s_lds[bcol * 161 + c * 16 + quad * 4 + r], scale * sacc[c][r]);
    __syncthreads();
    for (int k = t; k < 16 * CO; k += 256) {
        const int b = k / CO, j = k - b * CO;
        unsafeAtomicAdd(&sbuf[(size_t)(b0 + b) * CO + j], s_lds[b * 161 + j]);
    }
}

__global__ __launch_bounds__(256) void caps_squash_kernel(
    const float* __restrict__ rbias,   // [10, 16]
    float* __restrict__ sbuf,          // npart>0: part[npart][256][160]; else [256][160]
    float* __restrict__ vsum,          // [256, 10, 16]
    float* __restrict__ out_poses,     // [256, 10, 16]
    float* __restrict__ out_act,       // [256, 10]
    int it, int npart)
{
    const int b = blockIdx.x;
    const int t = threadIdx.x;
    if (t >= CO) return;
    const int c = t >> 4;

    const size_t idx = (size_t)b * CO + t;
    float s;
    if (npart > 0) {
        const float* p = sbuf + idx;
        const size_t stride = (size_t)NB * CO;
        float a0 = 0.f, a1 = 0.f, a2 = 0.f, a3 = 0.f;
        int px = 0;
        for (; px + 4 <= npart; px += 4) {
            a0 += p[(size_t)(px + 0) * stride];
            a1 += p[(size_t)(px + 1) * stride];
            a2 += p[(size_t)(px + 2) * stride];
            a3 += p[(size_t)(px + 3) * stride];
        }
        for (; px < npart; ++px) a0 += p[(size_t)px * stride];
        s = ((a0 + a1) + (a2 + a3)) + rbias[t];
    } else {
        s = sbuf[idx] + rbias[t];
    }

    float sq = s * s;
    sq += __shfl_xor(sq, 1);
    sq += __shfl_xor(sq, 2);
    sq += __shfl_xor(sq, 4);
    sq += __shfl_xor(sq, 8);
    const float f = (sq / (1.f + sq)) * rsqrtf(sq + CAPS_EPS);
    const float v = f * s;

    if (it < 2) {
        vsum[idx] += v;
        if (npart == 0) sbuf[idx] = 0.f;   // re-arm accumulator (legacy path)
    } else {
        out_poses[idx] = v;
        if ((t & 15) == 0) out_act[(size_t)b * NC + c] = sqrtf(f * f * sq + CAPS_EPS);
    }
}

extern "C" void kernel_launch(void* const* d_in, const int* in_sizes, int n_in,
                              void* d_out, int out_size, void* d_ws, size_t ws_size,
                              hipStream_t stream) {
    const float* poses  = (const float*)d_in[0];
    // d_in[1] (input_caps_activations) unused by the reference computation.
    const float* weight = (const float*)d_in[2];
    const float* rbias  = (const float*)d_in[3];

    float* out       = (float*)d_out;
    float* out_poses = out;                                   // 256*10*16
    float* out_act   = out + (size_t)NB * CO;                 // 256*10
    float* out_coup  = out_act + (size_t)NB * NC;             // 256*10*1152

    const size_t part_bytes = (size_t)PBLK * NB * CO * sizeof(float);  // 7.86 MB
    const size_t vsum_bytes = (size_t)NB * CO * sizeof(float);         // 160 KB
    const size_t frag_bytes = (size_t)(NA2 + NB2) * sizeof(uint2);     // 15.3 MB
    const size_t need_full  = part_bytes + vsum_bytes + frag_bytes;    // 23.4 MB

    if (ws_size >= need_full) {
        float* part = (float*)d_ws;
        float* vsum = part + (size_t)PBLK * NB * CO;
        uint2* wsA  = (uint2*)((char*)d_ws + part_bytes + vsum_bytes);
        uint2* wsB  = wsA + NA2;

        (void)hipMemsetAsync(vsum, 0, vsum_bytes, stream);
        hipLaunchKernelGGL(preconv2_kernel,
                           dim3((NA2 + NB2) / 256), dim3(256), 0, stream,
                           poses, weight, wsA, wsB);

        hipLaunchKernelGGL((caps_votes3<0>), dim3(PBLK, 16), dim3(256), 0, stream,
                           wsA, wsB, vsum, part, out_coup);
        hipLaunchKernelGGL(caps_squash_kernel, dim3(NB), dim3(256), 0, stream,
                           rbias, part, vsum, out_poses, out_act, 0, PBLK);
        hipLaunchKernelGGL((caps_votes3<1>), dim3(PBLK, 16), dim3(256), 0, stream,
                           wsA, wsB, vsum, part, out_coup);
        hipLaunchKernelGGL(caps_squash_kernel, dim3(NB), dim3(256), 0, stream,
                           rbias, part, vsum, out_poses, out_act, 1, PBLK);
        hipLaunchKernelGGL((caps_votes3<2>), dim3(PBLK, 16), dim3(256), 0, stream,
                           wsA, wsB, vsum, part, out_coup);
        hipLaunchKernelGGL(caps_squash_kernel, dim3(NB), dim3(256), 0, stream,
                           rbias, part, vsum, out_poses, out_act, 2, PBLK);
    } else {
        // legacy small-ws path: atomic accumulator
        float* sbuf = (float*)d_ws;
        float* vsum = sbuf + (size_t)NB * CO;
        (void)hipMemsetAsync(d_ws, 0, 2 * vsum_bytes, stream);
        for (int it = 0; it < 3; ++it) {
            hipLaunchKernelGGL(caps_votes_fb, dim3(PBLK, 16), dim3(256), 0, stream,
                               poses, weight, vsum, sbuf, out_coup, it);
            hipLaunchKernelGGL(caps_squash_kernel, dim3(NB), dim3(256), 0, stream,
                               rbias, sbuf, vsum, out_poses, out_act, it, 0);
        }
    }
}

// Round 5
// 280.045 us; speedup vs baseline: 1.2040x; 1.2040x over previous
//
#include <hip/hip_runtime.h>

// CapsClass2d dynamic routing — MFMA 16x16x16, global_load_lds pipelined.
// b=256, P=1152, C=10, os=is=16, 3 iterations.
//
// R4 post-mortem: WRITE_SIZE 208MB/dispatch = forced register spills
// (__launch_bounds__(256,3) capped unified VGPRs at ~168 vs ~175 live ->
// scratch traffic through TCC; R3 compile warned "final occupancy 1").
// FETCH 80MB = A-slice L2 thrash (16 b-tile sharers of each 120KB slice were
// 48 block-ids apart; per-XCD concurrent working set 11.5MB >> 4MB L2).
// Fixes:
//   1. __launch_bounds__(256) (no min-waves) + af[] batch removed (per-c
//      ds_read inline) -> no spills. ~155 live regs -> 3 waves/EU naturally.
//   2. XCD swizzle: 1D grid 768; xcd=n&7, j=n>>3, slice=xcd*6+(j>>4),
//      bt=j&15. Slice sharers adjacent on one XCD (spacing 8); per-XCD A
//      set = 6 slices = 720KB -> L2-resident; A/B each cross fabric once.
//   3. Keep m97 pipeline: per-wave LDS double buffer, GLL 16B, counted
//      vmcnt(5) steady state (never 0 mid-loop).
//
// MFMA 16x16x16 (K=16 exact): all 64 lanes carry data (8B/lane frags).
//   A[m=o][k=i]: m=lane&15, k=(lane>>4)*4+j
//   B[k=i][n=b]: n=lane&15, k=(lane>>4)*4+j
//   C/D: col(b)=lane&15, row(o)=(lane>>4)*4+reg
// Wave = 16 batches x 10 c x PW=6 positions; block = 4 waves same b-tile.
// Merge: LDS -> part[slice][b][j]; squash reduces 48 partials.

#define NPOS 1152
#define NC 10
#define OS 16
#define IS 16
#define NB 256
#define CO (NC * OS)            // 160
#define CAPS_EPS 1e-8f
#define PW 6                    // positions per wave
#define PBLK (NPOS / (4 * PW))  // 48 p-superblocks
#define PPB (4 * PW)            // 24 positions per block
#define NA2 (NPOS * NC * 64)    // A uint2 slots (737280, 5.9 MB)
#define NB2 (16 * NPOS * 64)    // B uint2 slots (1179648, 9.4 MB)
#define LDS_AU 1280             // u32 words per A buffer (5120 B = 10 frags)

typedef __attribute__((ext_vector_type(4))) short bf16x4;
typedef __attribute__((ext_vector_type(4))) _Float16 halfx4;
typedef __attribute__((ext_vector_type(4))) float floatx4;

// Branch 1: bf16 (present on gfx950 device pass, verified R3/R4).
// Branch 0: f16 fallback. Branch 2: host pass / unavailable -> inert stub.
#if __has_builtin(__builtin_amdgcn_mfma_f32_16x16x16bf16_1k)
  #define MFMA_KIND 1
#elif __has_builtin(__builtin_amdgcn_mfma_f32_16x16x16f16)
  #define MFMA_KIND 0
#else
  #define MFMA_KIND 2
#endif

#define GLL(gp, lp) __builtin_amdgcn_global_load_lds( \
    (const __attribute__((address_space(1))) unsigned int*)(gp), \
    (__attribute__((address_space(3))) unsigned int*)(lp), 16, 0, 0)

__device__ __forceinline__ unsigned f2bf_rne(float x) {
    union { float f; unsigned u; } v; v.f = x;
    return (v.u + 0x7FFFu + ((v.u >> 16) & 1u)) >> 16;
}

__device__ __forceinline__ uint2 pack4(float4 f) {
#if MFMA_KIND != 0
    uint2 r;
    r.x = f2bf_rne(f.x) | (f2bf_rne(f.y) << 16);
    r.y = f2bf_rne(f.z) | (f2bf_rne(f.w) << 16);
    return r;
#else
    union { uint2 u; halfx4 v; } r;
    r.v[0] = (_Float16)f.x; r.v[1] = (_Float16)f.y;
    r.v[2] = (_Float16)f.z; r.v[3] = (_Float16)f.w;
    return r.u;
#endif
}

__device__ __forceinline__ floatx4 MFMA16(uint2 a, uint2 b, floatx4 c) {
#if MFMA_KIND == 1
    union { uint2 u; bf16x4 v; } A, B; A.u = a; B.u = b;
    return __builtin_amdgcn_mfma_f32_16x16x16bf16_1k(A.v, B.v, c, 0, 0, 0);
#elif MFMA_KIND == 0
    union { uint2 u; halfx4 v; } A, B; A.u = a; B.u = b;
    return __builtin_amdgcn_mfma_f32_16x16x16f16(A.v, B.v, c, 0, 0, 0);
#else
    (void)a; (void)b;
    return c;   // host pass stub — never executed
#endif
}

// Pre-convert W and poses into 16x16x16 fragment-layout buffers (8B/lane/frag).
// wsA slot (p*10+c)*64+L : W[p][c][o=L&15][i=(L>>4)*4 ..+3]
// wsB slot (bt*1152+p)*64+L : X[bt*16+(L&15)][p][(L>>4)*4 ..+3]   (bt-major!)
__global__ __launch_bounds__(256) void preconv2_kernel(
    const float* __restrict__ poses, const float* __restrict__ weight,
    uint2* __restrict__ wsA, uint2* __restrict__ wsB)
{
    const int gid = blockIdx.x * 256 + threadIdx.x;
    if (gid < NA2) {
        const int L = gid & 63, pc = gid >> 6;
        const float4 src = *(const float4*)(weight + (size_t)pc * 256 + (L & 15) * 16 + (L >> 4) * 4);
        wsA[gid] = pack4(src);
    } else {
        const int s = gid - NA2;
        if (s < NB2) {
            const int L = s & 63, bp = s >> 6;
            const int p = bp % NPOS, bt = bp / NPOS;
            const float4 src = *(const float4*)(poses +
                ((size_t)(bt * 16 + (L & 15)) * NPOS + p) * IS + (L >> 4) * 4);
            wsB[s] = pack4(src);
        }
    }
}

template <int IT>
__global__ __launch_bounds__(256) void caps_votes3(
    const uint2* __restrict__ wsA, const uint2* __restrict__ wsB,
    const float* __restrict__ vsum, float* __restrict__ part,
    float* __restrict__ out_coup)
{
    const int t    = threadIdx.x;
    const int wave = t >> 6, lane = t & 63;
    const int bcol = lane & 15, quad = lane >> 4;

    // XCD-aware decode: consecutive block ids round-robin the 8 XCDs.
    // Give each XCD 6 whole slices; the 16 b-tile sharers of a slice are
    // spaced 8 apart (adjacent within the XCD's dispatch stream).
    const int n    = blockIdx.x;            // 0..767
    const int xcd  = n & 7, j = n >> 3;     // j: 0..95
    const int slice = xcd * (PBLK / 8) + (j >> 4);   // 0..47
    const int bt   = j & 15;
    const int b0   = bt * 16;
    const int pbase = slice * PPB + wave * PW;

    __shared__ unsigned ldsA[4][2][LDS_AU];     // per-wave A double buffer (40 KB)
    __shared__ float s_lds[16 * 161];           // merge buffer (+1 pad)

    for (int k = t; k < 16 * 161; k += 256) s_lds[k] = 0.f;

    float4 vs[NC];
    if (IT > 0) {
        const float* vp = vsum + (size_t)(b0 + bcol) * CO + quad * 4;
#pragma unroll
        for (int c = 0; c < NC; ++c) vs[c] = *(const float4*)(vp + c * 16);
    }
    __syncthreads();

    // B frags for all PW positions -> VGPRs (6 independent 8B loads)
    uint2 bfr[PW];
    {
        const uint2* bp = wsB + ((size_t)bt * NPOS + pbase) * 64 + lane;
#pragma unroll
        for (int pi = 0; pi < PW; ++pi) bfr[pi] = bp[pi * 64];
    }

    // A staging: per-wave lds double buffer; 5 x 1024B gll per position.
    const char* gA = (const char*)(wsA + (size_t)pbase * NC * 64) + lane * 16;
    unsigned* lA = &ldsA[wave][0][0];
#pragma unroll
    for (int ch = 0; ch < 5; ++ch) GLL(gA + ch * 1024, lA + ch * 256);
#pragma unroll
    for (int ch = 0; ch < 5; ++ch) GLL(gA + 5120 + ch * 1024, lA + LDS_AU + ch * 256);

    floatx4 sacc[NC];
#pragma unroll
    for (int c = 0; c < NC; ++c) sacc[c] = (floatx4)(0.f);

#pragma unroll
    for (int pi = 0; pi < PW; ++pi) {
        unsigned* buf = lA + (pi & 1) * LDS_AU;
        // counted wait: current buffer (and B regs / prior stores) landed;
        // next buffer's 5 loads stay in flight.
        if (pi < PW - 1) { asm volatile("s_waitcnt vmcnt(5)" ::: "memory"); }
        else             { asm volatile("s_waitcnt vmcnt(0)" ::: "memory"); }

        if (IT == 0) {
#pragma unroll
            for (int c = 0; c < NC; ++c) {
                const uint2 af = *(const uint2*)((const char*)buf + c * 512 + lane * 8);
                sacc[c] = MFMA16(af, bfr[pi], sacc[c]);
            }
            if (pi < PW - 2) {
                asm volatile("s_waitcnt lgkmcnt(0)" ::: "memory");  // ds_reads of buf done
                const char* g = gA + (size_t)(pi + 2) * 5120;
#pragma unroll
                for (int ch = 0; ch < 5; ++ch) GLL(g + ch * 1024, buf + ch * 256);
            }
        } else {
            floatx4 acc[NC];
#pragma unroll
            for (int c = 0; c < NC; ++c) {
                const uint2 af = *(const uint2*)((const char*)buf + c * 512 + lane * 8);
                acc[c] = MFMA16(af, bfr[pi], (floatx4)(0.f));
            }

            // logits: dot over o = (quad,reg); 4 FMA + 2 shfl per c
            float lg[NC];
            float mx = -1e30f;
#pragma unroll
            for (int c = 0; c < NC; ++c) {
                float pt = vs[c].x * acc[c][0] + vs[c].y * acc[c][1]
                         + vs[c].z * acc[c][2] + vs[c].w * acc[c][3];
                pt += __shfl_xor(pt, 16);
                pt += __shfl_xor(pt, 32);
                lg[c] = pt;
                mx = fmaxf(mx, pt);
            }
            float coup[NC];
            float sum = 0.f;
#pragma unroll
            for (int c = 0; c < NC; ++c) { coup[c] = __expf(lg[c] - mx); sum += coup[c]; }
            const float inv = 1.f / sum;
#pragma unroll
            for (int c = 0; c < NC; ++c) coup[c] *= inv;

            if (IT == 2 && quad == 0) {
                // direct scatter; p innermost out_coup dim -> L2 write-back
                // coalesces. Issued BEFORE restage GLL so the next vmcnt(5)
                // drains these, not the prefetch.
                float* cp = out_coup + (size_t)(b0 + bcol) * (NC * NPOS) + (pbase + pi);
#pragma unroll
                for (int c = 0; c < NC; ++c) cp[c * NPOS] = coup[c];
            }

            if (pi < PW - 2) {
                asm volatile("s_waitcnt lgkmcnt(0)" ::: "memory");  // ds_reads of buf done
                const char* g = gA + (size_t)(pi + 2) * 5120;
#pragma unroll
                for (int ch = 0; ch < 5; ++ch) GLL(g + ch * 1024, buf + ch * 256);
            }

#pragma unroll
            for (int c = 0; c < NC; ++c)
#pragma unroll
                for (int r = 0; r < 4; ++r) sacc[c][r] += coup[c] * acc[c][r];
        }
    }

    // merge the block's 4 waves in LDS, then coalesced partial store
    const float scale = (IT == 0) ? 0.1f : 1.f;
#pragma unroll
    for (int c = 0; c < NC; ++c)
#pragma unroll
        for (int r = 0; r < 4; ++r)
            atomicAdd(&s_lds[bcol * 161 + c * 16 + quad * 4 + r], scale * sacc[c][r]);
    __syncthreads();

    float* pp = part + ((size_t)slice * NB + b0) * CO;
    for (int k = t; k < 16 * CO; k += 256) {
        const int b = k / CO, jj = k - b * CO;
        pp[(size_t)b * CO + jj] = s_lds[b * 161 + jj];
    }
}

// Fallback (tiny ws): direct float4 loads + in-register conversion, atomic merge.
__global__ __launch_bounds__(256) void caps_votes_fb(
    const float* __restrict__ poses, const float* __restrict__ weight,
    const float* __restrict__ vsum, float* __restrict__ sbuf,
    float* __restrict__ out_coup, int it)
{
    const int t = threadIdx.x, wave = t >> 6, lane = t & 63;
    const int bcol = lane & 15, quad = lane >> 4;
    const int bt = blockIdx.y, b0 = bt * 16;
    const int pbase = blockIdx.x * PPB + wave * PW;

    __shared__ float s_lds[16 * 161];
    for (int k = t; k < 16 * 161; k += 256) s_lds[k] = 0.f;

    float4 vs[NC];
    if (it > 0) {
        const float* vp = vsum + (size_t)(b0 + bcol) * CO + quad * 4;
#pragma unroll
        for (int c = 0; c < NC; ++c) vs[c] = *(const float4*)(vp + c * 16);
    }
    __syncthreads();

    floatx4 sacc[NC];
#pragma unroll
    for (int c = 0; c < NC; ++c) sacc[c] = (floatx4)(0.f);

    for (int pi = 0; pi < PW; ++pi) {
        const int p = pbase + pi;
        const uint2 bfrag = pack4(*(const float4*)(poses +
            ((size_t)(b0 + bcol) * NPOS + p) * IS + quad * 4));
        floatx4 acc[NC];
#pragma unroll
        for (int c = 0; c < NC; ++c) {
            const uint2 a = pack4(*(const float4*)(weight +
                (size_t)(p * NC + c) * 256 + bcol * 16 + quad * 4));
            acc[c] = MFMA16(a, bfrag, (floatx4)(0.f));
        }
        if (it == 0) {
#pragma unroll
            for (int c = 0; c < NC; ++c)
#pragma unroll
                for (int r = 0; r < 4; ++r) sacc[c][r] += acc[c][r];
        } else {
            float lg[NC], mx = -1e30f;
#pragma unroll
            for (int c = 0; c < NC; ++c) {
                float pt = vs[c].x * acc[c][0] + vs[c].y * acc[c][1]
                         + vs[c].z * acc[c][2] + vs[c].w * acc[c][3];
                pt += __shfl_xor(pt, 16);
                pt += __shfl_xor(pt, 32);
                lg[c] = pt; mx = fmaxf(mx, pt);
            }
            float coup[NC], sum = 0.f;
#pragma unroll
            for (int c = 0; c < NC; ++c) { coup[c] = __expf(lg[c] - mx); sum += coup[c]; }
            const float inv = 1.f / sum;
#pragma unroll
            for (int c = 0; c < NC; ++c) coup[c] *= inv;
            if (it == 2 && quad == 0) {
                float* cp = out_coup + (size_t)(b0 + bcol) * (NC * NPOS) + p;
#pragma unroll
                for (int c = 0; c < NC; ++c) cp[c * NPOS] = coup[c];
            }
#pragma unroll
            for (int c = 0; c < NC; ++c)
#pragma unroll
                for (int r = 0; r < 4; ++r) sacc[c][r] += coup[c] * acc[c][r];
        }
    }

    const float scale = (it == 0) ? 0.1f : 1.f;
#pragma unroll
    for (int c = 0; c < NC; ++c)
#pragma unroll
        for (int r = 0; r < 4; ++r)
            atomicAdd(&s_lds[bcol * 161 + c * 16 + quad * 4 + r], scale * sacc[c][r]);
    __syncthreads();
    for (int k = t; k < 16 * CO; k += 256) {
        const int b = k / CO, j = k - b * CO;
        unsafeAtomicAdd(&sbuf[(size_t)(b0 + b) * CO + j], s_lds[b * 161 + j]);
    }
}

__global__ __launch_bounds__(256) void caps_squash_kernel(
    const float* __restrict__ rbias,   // [10, 16]
    float* __restrict__ sbuf,          // npart>0: part[npart][256][160]; else [256][160]
    float* __restrict__ vsum,          // [256, 10, 16]
    float* __restrict__ out_poses,     // [256, 10, 16]
    float* __restrict__ out_act,       // [256, 10]
    int it, int npart)
{
    const int b = blockIdx.x;
    const int t = threadIdx.x;
    if (t >= CO) return;
    const int c = t >> 4;

    const size_t idx = (size_t)b * CO + t;
    float s;
    if (npart > 0) {
        const float* p = sbuf + idx;
        const size_t stride = (size_t)NB * CO;
        float a0 = 0.f, a1 = 0.f, a2 = 0.f, a3 = 0.f;
        int px = 0;
        for (; px + 4 <= npart; px += 4) {
            a0 += p[(size_t)(px + 0) * stride];
            a1 += p[(size_t)(px + 1) * stride];
            a2 += p[(size_t)(px + 2) * stride];
            a3 += p[(size_t)(px + 3) * stride];
        }
        for (; px < npart; ++px) a0 += p[(size_t)px * stride];
        s = ((a0 + a1) + (a2 + a3)) + rbias[t];
    } else {
        s = sbuf[idx] + rbias[t];
    }

    float sq = s * s;
    sq += __shfl_xor(sq, 1);
    sq += __shfl_xor(sq, 2);
    sq += __shfl_xor(sq, 4);
    sq += __shfl_xor(sq, 8);
    const float f = (sq / (1.f + sq)) * rsqrtf(sq + CAPS_EPS);
    const float v = f * s;

    if (it < 2) {
        vsum[idx] += v;
        if (npart == 0) sbuf[idx] = 0.f;   // re-arm accumulator (legacy path)
    } else {
        out_poses[idx] = v;
        if ((t & 15) == 0) out_act[(size_t)b * NC + c] = sqrtf(f * f * sq + CAPS_EPS);
    }
}

extern "C" void kernel_launch(void* const* d_in, const int* in_sizes, int n_in,
                              void* d_out, int out_size, void* d_ws, size_t ws_size,
                              hipStream_t stream) {
    const float* poses  = (const float*)d_in[0];
    // d_in[1] (input_caps_activations) unused by the reference computation.
    const float* weight = (const float*)d_in[2];
    const float* rbias  = (const float*)d_in[3];

    float* out       = (float*)d_out;
    float* out_poses = out;                                   // 256*10*16
    float* out_act   = out + (size_t)NB * CO;                 // 256*10
    float* out_coup  = out_act + (size_t)NB * NC;             // 256*10*1152

    const size_t part_bytes = (size_t)PBLK * NB * CO * sizeof(float);  // 7.86 MB
    const size_t vsum_bytes = (size_t)NB * CO * sizeof(float);         // 160 KB
    const size_t frag_bytes = (size_t)(NA2 + NB2) * sizeof(uint2);     // 15.3 MB
    const size_t need_full  = part_bytes + vsum_bytes + frag_bytes;    // 23.4 MB

    if (ws_size >= need_full) {
        float* part = (float*)d_ws;
        float* vsum = part + (size_t)PBLK * NB * CO;
        uint2* wsA  = (uint2*)((char*)d_ws + part_bytes + vsum_bytes);
        uint2* wsB  = wsA + NA2;

        (void)hipMemsetAsync(vsum, 0, vsum_bytes, stream);
        hipLaunchKernelGGL(preconv2_kernel,
                           dim3((NA2 + NB2) / 256), dim3(256), 0, stream,
                           poses, weight, wsA, wsB);

        hipLaunchKernelGGL((caps_votes3<0>), dim3(PBLK * 16), dim3(256), 0, stream,
                           wsA, wsB, vsum, part, out_coup);
        hipLaunchKernelGGL(caps_squash_kernel, dim3(NB), dim3(256), 0, stream,
                           rbias, part, vsum, out_poses, out_act, 0, PBLK);
        hipLaunchKernelGGL((caps_votes3<1>), dim3(PBLK * 16), dim3(256), 0, stream,
                           wsA, wsB, vsum, part, out_coup);
        hipLaunchKernelGGL(caps_squash_kernel, dim3(NB), dim3(256), 0, stream,
                           rbias, part, vsum, out_poses, out_act, 1, PBLK);
        hipLaunchKernelGGL((caps_votes3<2>), dim3(PBLK * 16), dim3(256), 0, stream,
                           wsA, wsB, vsum, part, out_coup);
        hipLaunchKernelGGL(caps_squash_kernel, dim3(NB), dim3(256), 0, stream,
                           rbias, part, vsum, out_poses, out_act, 2, PBLK);
    } else {
        // legacy small-ws path: atomic accumulator
        float* sbuf = (float*)d_ws;
        float* vsum = sbuf + (size_t)NB * CO;
        (void)hipMemsetAsync(d_ws, 0, 2 * vsum_bytes, stream);
        for (int it = 0; it < 3; ++it) {
            hipLaunchKernelGGL(caps_votes_fb, dim3(PBLK, 16), dim3(256), 0, stream,
                               poses, weight, vsum, sbuf, out_coup, it);
            hipLaunchKernelGGL(caps_squash_kernel, dim3(NB), dim3(256), 0, stream,
                               rbias, sbuf, vsum, out_poses, out_act, it, 0);
        }
    }
}